// Round 1
// baseline (11474.085 us; speedup 1.0000x reference)
//
#include <hip/hip_runtime.h>
#include <hip/hip_bf16.h>

#define TT 127   // timesteps (T-1)
#define PP 256   // decoder hidden
#define MM 256   // encoder hidden

__device__ __forceinline__ float bf2f(unsigned short u){
  union { unsigned int i; float f; } v; v.i = ((unsigned int)u) << 16; return v.f;
}
__device__ __forceinline__ unsigned short f2bf(float f){
  union { float f; unsigned int i; } v; v.f = f;
  unsigned int r = v.i + 0x7FFFu + ((v.i >> 16) & 1u);
  return (unsigned short)(r >> 16);
}
__device__ __forceinline__ float fexp2(float x){ return __builtin_amdgcn_exp2f(x); }
__device__ __forceinline__ float frcp(float x){ return __builtin_amdgcn_rcpf(x); }
__device__ __forceinline__ float sigm(float x){
  return frcp(1.f + fexp2(-1.4426950408889634f * x));
}
__device__ __forceinline__ float tanh_f(float x){
  // tanh(x) = 1 - 2/(exp(2x)+1), exp(2x) = exp2(2*log2e*x)
  return 1.f - 2.f * frcp(1.f + fexp2(2.8853900817779268f * x));
}

// ---------- prep: weight transposes (tiny, uncoalesced-ok) ----------
__global__ void k_tr_w1dc(const float* __restrict__ W1, float* __restrict__ W1dcT){
  int idx = blockIdx.x * 256 + threadIdx.x;   // 512*256
  int i = idx >> 8, h = idx & 255;
  W1dcT[idx] = W1[h * 768 + i];
}
__global__ void k_tr_whh(const float* __restrict__ Whh, float* __restrict__ WhhT){
  int idx = blockIdx.x * 256 + threadIdx.x;   // 256*1024
  int i = idx >> 10, g = idx & 1023;
  WhhT[idx] = Whh[g * 256 + i];
}
__global__ void k_tr_w1x(const float* __restrict__ W1, float* __restrict__ W1xT){
  int idx = blockIdx.x * 256 + threadIdx.x;   // 256*256
  int k = idx >> 8, h = idx & 255;
  W1xT[idx] = W1[h * 768 + 512 + k];
}

// ---------- prep: Tx[b,t,h] = tanh( sum_m X[b,t,m]*W1[h,512+m] + b1[h] ), bf16 ----------
__global__ __launch_bounds__(256) void k_gemm_tx(
    const float* __restrict__ X, const float* __restrict__ W1xT,
    const float* __restrict__ b1, unsigned short* __restrict__ Tx)
{
  __shared__ float As[16][64];   // [k][row]
  __shared__ float Bs[16][64];   // [k][col]
  const int row0 = blockIdx.x * 64;   // rows = 1024*127 = 130048 = 2032*64
  const int col0 = blockIdx.y * 64;   // cols = 256 = 4*64
  const int tid = threadIdx.x;
  const int tx = tid & 15, ty = tid >> 4;
  float acc[4][4] = {};
  for (int k0 = 0; k0 < 256; k0 += 16) {
    {
      const int rr = tid & 63, kk4 = (tid >> 6) << 2;
      float4 v = *(const float4*)&X[(size_t)(row0 + rr) * 256 + k0 + kk4];
      As[kk4 + 0][rr] = v.x; As[kk4 + 1][rr] = v.y;
      As[kk4 + 2][rr] = v.z; As[kk4 + 3][rr] = v.w;
    }
    {
      const int cc = tid & 63, kb = tid >> 6;
      #pragma unroll
      for (int j = 0; j < 4; ++j)
        Bs[kb + 4 * j][cc] = W1xT[(size_t)(k0 + kb + 4 * j) * 256 + col0 + cc];
    }
    __syncthreads();
    #pragma unroll
    for (int kk = 0; kk < 16; ++kk) {
      float4 a4 = *(const float4*)&As[kk][ty << 2];
      float4 b4 = *(const float4*)&Bs[kk][tx << 2];
      float av[4] = {a4.x, a4.y, a4.z, a4.w};
      float bv[4] = {b4.x, b4.y, b4.z, b4.w};
      #pragma unroll
      for (int i = 0; i < 4; ++i)
        #pragma unroll
        for (int j = 0; j < 4; ++j)
          acc[i][j] = fmaf(av[i], bv[j], acc[i][j]);
    }
    __syncthreads();
  }
  const int c = col0 + (tx << 2);
  #pragma unroll
  for (int i = 0; i < 4; ++i) {
    const int r = row0 + (ty << 2) + i;
    ushort4 o;
    o.x = f2bf(tanhf(acc[i][0] + b1[c + 0]));
    o.y = f2bf(tanhf(acc[i][1] + b1[c + 1]));
    o.z = f2bf(tanhf(acc[i][2] + b1[c + 2]));
    o.w = f2bf(tanhf(acc[i][3] + b1[c + 3]));
    *(ushort4*)&Tx[(size_t)r * 256 + c] = o;
  }
}

// ---------- main: 256 blocks x 1024 threads; block owns 4 batch elems for all 127 steps ----------
__global__ __launch_bounds__(1024, 4) void k_main(
    const float* __restrict__ X,
    const unsigned short* __restrict__ Tx,
    const float* __restrict__ W1dcT,   // f32 [512][256]
    const float* __restrict__ WhhT,    // f32 [256][1024]
    const float* __restrict__ yprev,
    const float* __restrict__ W2,
    const float* __restrict__ Wih,
    const float* __restrict__ bih,
    const float* __restrict__ bhh,
    const float* __restrict__ fcW,
    const float* __restrict__ fcb,
    const float* __restrict__ fcfW,
    const float* __restrict__ fcfb,
    float* __restrict__ out)
{
  __shared__ float dc[4][512];     // d: [0,256) c: [256,512)
  __shared__ float us[4][256];     // Tu = tanh(u)
  __shared__ float sc[4][128];     // scores -> beta
  __shared__ float ctx[4][256];
  __shared__ float gts[4][1024];
  __shared__ float ytil[4];
  __shared__ float w2s[256];
  __shared__ float fcw_s[257];
  __shared__ float fcfw_s[512];
  __shared__ float wih_s[1024];
  __shared__ float bsum_s[1024];

  const int tid = threadIdx.x;
  const int b0 = blockIdx.x << 2;
  const int lane = tid & 63;
  const int wv = tid >> 6;        // wave 0..15
  const int bb = tid >> 8;        // 0..3
  const int hq = tid & 255;       // 0..255

  if (tid < 256) w2s[tid] = W2[tid];
  if (tid < 257) fcw_s[tid] = fcW[tid];
  if (tid < 512) fcfw_s[tid] = fcfW[tid];
  wih_s[tid] = Wih[tid];
  bsum_s[tid] = bih[tid] + bhh[tid];
  dc[bb][hq] = 0.f;
  dc[bb][256 + hq] = 0.f;
  __syncthreads();

  for (int t = 0; t < TT; ++t) {
    // ---- A: Tu = tanh([d,c] @ W1dc^T);  A2: gates partial = d @ Whh^T ----
    float gp0 = 0.f, gp1 = 0.f, gp2 = 0.f, gp3 = 0.f;
    {
      float acc = 0.f;
      #pragma unroll 8
      for (int i = 0; i < 512; ++i)
        acc = fmaf(dc[bb][i], W1dcT[(i << 8) + hq], acc);
      us[bb][hq] = tanh_f(acc);

      const int g4 = hq << 2;
      #pragma unroll 4
      for (int i = 0; i < 256; ++i) {
        const float dv = dc[bb][i];
        const float4 w = *(const float4*)&WhhT[(size_t)(i << 10) + g4];
        gp0 = fmaf(dv, w.x, gp0);
        gp1 = fmaf(dv, w.y, gp1);
        gp2 = fmaf(dv, w.z, gp2);
        gp3 = fmaf(dv, w.w, gp3);
      }
    }
    __syncthreads();

    // ---- B: scores[bq][tt] = sum_h W2[h] * tanh(u+z) via addition formula ----
    {
      const int bq = wv >> 2;
      const int h4 = lane << 2;
      const float4 tu = *(const float4*)&us[bq][h4];
      const float4 w4 = *(const float4*)&w2s[h4];
      const unsigned short* txp = &Tx[((size_t)(b0 + bq) * TT) * 256 + h4];
      for (int tt = (wv & 3); tt < TT; tt += 4) {
        const ushort4 xr = *(const ushort4*)&txp[(size_t)tt << 8];
        const float x0 = bf2f(xr.x), x1 = bf2f(xr.y), x2 = bf2f(xr.z), x3 = bf2f(xr.w);
        float acc;
        acc =      w4.x * ((tu.x + x0) * frcp(fmaf(tu.x, x0, 1.f)));
        acc = fmaf(w4.y,  (tu.y + x1) * frcp(fmaf(tu.y, x1, 1.f)), acc);
        acc = fmaf(w4.z,  (tu.z + x2) * frcp(fmaf(tu.z, x2, 1.f)), acc);
        acc = fmaf(w4.w,  (tu.w + x3) * frcp(fmaf(tu.w, x3, 1.f)), acc);
        #pragma unroll
        for (int m = 32; m; m >>= 1) acc += __shfl_xor(acc, m);
        if (lane == 0) sc[bq][tt] = acc;
      }
    }
    __syncthreads();

    // ---- softmax over tt (waves 0..3, one per bb); +b2 dropped (softmax-invariant) ----
    if (wv < 4) {
      const float s0 = sc[wv][lane];
      const float s1 = (lane < 63) ? sc[wv][lane + 64] : -3.0e38f;
      float mx = fmaxf(s0, s1);
      #pragma unroll
      for (int m = 32; m; m >>= 1) mx = fmaxf(mx, __shfl_xor(mx, m));
      const float p0 = fexp2((s0 - mx) * 1.4426950408889634f);
      const float p1 = (lane < 63) ? fexp2((s1 - mx) * 1.4426950408889634f) : 0.f;
      float sm = p0 + p1;
      #pragma unroll
      for (int m = 32; m; m >>= 1) sm += __shfl_xor(sm, m);
      const float inv = frcp(sm);
      sc[wv][lane] = p0 * inv;
      if (lane < 63) sc[wv][lane + 64] = p1 * inv;
    }
    __syncthreads();

    // ---- C: context[bb][m] = sum_t beta * X (exact f32 X) ----
    {
      float acc = 0.f;
      const float* xp = &X[((size_t)(b0 + bb) * TT) * 256 + hq];
      #pragma unroll 4
      for (int tt = 0; tt < TT; ++tt)
        acc = fmaf(sc[bb][tt], xp[(size_t)tt << 8], acc);
      ctx[bb][hq] = acc;
    }
    __syncthreads();

    // ---- D1: y_tilde (waves 0..3) ----
    if (wv < 4) {
      float a = 0.f;
      #pragma unroll
      for (int j = 0; j < 4; ++j) {
        const int m = lane + (j << 6);
        a = fmaf(ctx[wv][m], fcw_s[m], a);
      }
      #pragma unroll
      for (int m = 32; m; m >>= 1) a += __shfl_xor(a, m);
      if (lane == 0)
        ytil[wv] = a + fcw_s[256] * yprev[(size_t)(b0 + wv) * TT + t] + fcb[0];
    }
    __syncthreads();

    // ---- D2: gates = partial + y_tilde*W_ih + (b_ih+b_hh) ----
    {
      const int g4 = hq << 2;
      const float yt = ytil[bb];
      float4 gv;
      gv.x = gp0 + yt * wih_s[g4 + 0] + bsum_s[g4 + 0];
      gv.y = gp1 + yt * wih_s[g4 + 1] + bsum_s[g4 + 1];
      gv.z = gp2 + yt * wih_s[g4 + 2] + bsum_s[g4 + 2];
      gv.w = gp3 + yt * wih_s[g4 + 3] + bsum_s[g4 + 3];
      *(float4*)&gts[bb][g4] = gv;
    }
    __syncthreads();

    // ---- D3: LSTM pointwise update ----
    {
      const float gi = gts[bb][hq];
      const float gf = gts[bb][hq + 256];
      const float gg = gts[bb][hq + 512];
      const float go = gts[bb][hq + 768];
      const float cn = sigm(gf) * dc[bb][256 + hq] + sigm(gi) * tanh_f(gg);
      const float dn = sigm(go) * tanh_f(cn);
      dc[bb][hq] = dn;
      dc[bb][256 + hq] = cn;
    }
    __syncthreads();
  }

  // ---- output: y_pred = [d, context] @ fcfW^T + fcfb ----
  if (wv < 4) {
    float a = 0.f;
    #pragma unroll
    for (int j = 0; j < 4; ++j) {
      const int m = lane + (j << 6);
      a = fmaf(dc[wv][m], fcfw_s[m], a);
      a = fmaf(ctx[wv][m], fcfw_s[256 + m], a);
    }
    #pragma unroll
    for (int m = 32; m; m >>= 1) a += __shfl_xor(a, m);
    if (lane == 0) out[b0 + wv] = a + fcfb[0];
  }
}

extern "C" void kernel_launch(void* const* d_in, const int* in_sizes, int n_in,
                              void* d_out, int out_size, void* d_ws, size_t ws_size,
                              hipStream_t stream) {
  const float* X    = (const float*)d_in[0];
  const float* yprev= (const float*)d_in[1];
  const float* W1   = (const float*)d_in[2];
  const float* b1   = (const float*)d_in[3];
  const float* W2   = (const float*)d_in[4];
  // d_in[5] = attn_b2: softmax-invariant, unused
  const float* Wih  = (const float*)d_in[6];
  const float* Whh  = (const float*)d_in[7];
  const float* bih  = (const float*)d_in[8];
  const float* bhh  = (const float*)d_in[9];
  const float* fcW  = (const float*)d_in[10];
  const float* fcb  = (const float*)d_in[11];
  const float* fcfW = (const float*)d_in[12];
  const float* fcfb = (const float*)d_in[13];
  float* out = (float*)d_out;

  size_t off = 0;
  char* base = (char*)d_ws;
  auto alloc = [&](size_t bytes) -> void* {
    void* p = base + off;
    off += (bytes + 255) & ~(size_t)255;
    return p;
  };
  unsigned short* Tx = (unsigned short*)alloc((size_t)1024 * TT * 256 * 2);
  float* W1dcT = (float*)alloc((size_t)512 * 256 * 4);
  float* WhhT  = (float*)alloc((size_t)256 * 1024 * 4);
  float* W1xT  = (float*)alloc((size_t)256 * 256 * 4);
  (void)ws_size; (void)in_sizes; (void)n_in; (void)out_size;

  k_tr_w1dc<<<512, 256, 0, stream>>>(W1, W1dcT);
  k_tr_whh<<<1024, 256, 0, stream>>>(Whh, WhhT);
  k_tr_w1x<<<256, 256, 0, stream>>>(W1, W1xT);
  dim3 gg(2032, 4);
  k_gemm_tx<<<gg, 256, 0, stream>>>(X, W1xT, b1, Tx);
  k_main<<<256, 1024, 0, stream>>>(X, Tx, W1dcT, WhhT, yprev, W2,
                                   Wih, bih, bhh, fcW, fcb, fcfW, fcfb, out);
}